// Round 8
// baseline (57.937 us; speedup 1.0000x reference)
//
#include <hip/hip_runtime.h>
#include <stdint.h>

#define K_DIM 4096
#define N_DIM 11008
#define M_DIM 256

typedef uint32_t u32;
using frag_ab = __attribute__((ext_vector_type(8))) short;   // 8 bf16
using frag_cd = __attribute__((ext_vector_type(4))) float;   // 4 f32
using u32x2   = __attribute__((ext_vector_type(2))) uint32_t;

typedef __attribute__((address_space(3))) const char lds_cc;

// Inline-asm LDS reads: opaque to the compiler's waitcnt pass, so our counted
// vmcnt (not an auto-inserted vmcnt(0)) governs the global_load_lds queue.
#define DSR128(dst, addr, off)                                       \
    asm volatile("ds_read_b128 %0, %1 offset:" #off                  \
                 : "=&v"(dst) : "v"(addr))
#define DSR2(dst, addr, o0, o1)                                      \
    asm volatile("ds_read2_b32 %0, %1 offset0:" #o0 " offset1:" #o1  \
                 : "=&v"(dst) : "v"(addr))

__device__ __forceinline__ u32 f2bf_rn(float f) {
    u32 u = __builtin_bit_cast(u32, f);
    return (u + 0x7FFFu + ((u >> 16) & 1u)) >> 16;   // round-to-nearest-even
}
__device__ __forceinline__ float bf2f(u32 b) {
    return __builtin_bit_cast(float, b << 16);
}
__device__ __forceinline__ void gll16(const void* g, void* l) {
    __builtin_amdgcn_global_load_lds(
        (const __attribute__((address_space(1))) u32*)g,
        (__attribute__((address_space(3))) u32*)l, 16, 0, 0);
}

// bf16(32+v) = 0x4200 | (v<<2).  For packed byte q = hi<<4|lo:
// q*0x4004 = q<<14 | q<<2 (no carries); mask -> {32+lo, 32+hi} bf16x2.
#define BFCVT(q) ((u32)((__mul24((int)(q), 0x4004) & 0x003C003C) | 0x42004200))

// Kernel 1: x f32 -> bf16 (RN) + per-row sums of the ROUNDED values.
__global__ __launch_bounds__(256) void prep_kernel(const float* __restrict__ x,
                                                   ushort* __restrict__ xbf,
                                                   float* __restrict__ rowsum) {
    const int row = blockIdx.x;
    const int tid = threadIdx.x;
    const float* xr = x + (size_t)row * K_DIM;
    ushort* br = xbf + (size_t)row * K_DIM;
    float s = 0.0f;
#pragma unroll
    for (int p = 0; p < 4; ++p) {
        int i = p * 1024 + tid * 4;
        float4 v = *reinterpret_cast<const float4*>(xr + i);
        u32 b0 = f2bf_rn(v.x), b1 = f2bf_rn(v.y), b2 = f2bf_rn(v.z), b3 = f2bf_rn(v.w);
        uint2 o;
        o.x = b0 | (b1 << 16);
        o.y = b2 | (b3 << 16);
        *reinterpret_cast<uint2*>(br + i) = o;
        s += bf2f(b0) + bf2f(b1) + bf2f(b2) + bf2f(b3);
    }
#pragma unroll
    for (int off = 32; off > 0; off >>= 1) s += __shfl_down(s, off, 64);
    __shared__ float wsum[4];
    if ((tid & 63) == 0) wsum[tid >> 6] = s;
    __syncthreads();
    if (tid == 0) rowsum[row] = wsum[0] + wsum[1] + wsum[2] + wsum[3];
}

// Kernel 2: out = xbf @ dequant(qw).  BM=128, BN=64, BK=32, split-K=2.
// Small tiles -> 36 KB LDS triple-buffer -> 4 blocks/CU (16 waves/CU): TLP
// hides whatever the per-block pipeline can't.  Counted vmcnt + raw
// s_barrier + inline-asm LDS reads keep the gll queue un-drained.
__global__ __launch_bounds__(256, 4) void gemm_kernel(const int* __restrict__ qw,
                                                      const float* __restrict__ scales,
                                                      const float* __restrict__ zeroes,
                                                      const ushort* __restrict__ xbf,
                                                      const float* __restrict__ rowsum,
                                                      float* __restrict__ out,
                                                      float* __restrict__ partial,
                                                      int split2) {
    // A tile: [m 0..127] rows of 32 bf16 (4 chunks of 16B), chunk stored at
    //         chunk' = chunk ^ ((m>>1)&3)  -> 2-way max on ds_read_b128 (free)
    // B tile: [row 0..15][col 0..63] packed dwords, col stored ^ ((row>>2&1)<<4)
    __shared__ uint4 Alds[3][512];    // 3 x 8 KB
    __shared__ u32   Blds[3][1024];   // 3 x 4 KB

    const u32* qwu = (const u32*)qw;
    const int tid  = threadIdx.x;
    const int lane = tid & 63;
    const int wid  = tid >> 6;
    const int l4   = lane & 15;
    const int c    = lane >> 4;

    // XCD-bijective swizzle; all blocks of one n-tile land on the same XCD.
    const int orig = blockIdx.x;
    int nb, mb, sp, NTt;
    if (split2) {
        int wg = (orig & 7) * 86 + (orig >> 3);   // 688 = 8*86
        nb = wg >> 2; mb = (wg >> 1) & 1; sp = wg & 1; NTt = 64;
    } else {
        int wg = (orig & 7) * 43 + (orig >> 3);   // 344 = 8*43
        nb = wg >> 1; mb = wg & 1; sp = 0; NTt = 128;
    }
    const int n0 = nb * 64;
    const int m0 = mb * 128;
    const int kb = sp * 64;          // tile index base (tiles of 32 k)
    const int wm = wid >> 1;
    const int wn = wid & 1;

    // ---- staging sources (pre-swizzled so linear LDS dest = swizzled layout)
    // A gll j (j=0,1): lane covers m = (wid*2+j)*16 + (lane>>2),
    //                  global chunk = (lane&3) ^ ((lane>>3)&3)
    const ushort* asrc[2];
#pragma unroll
    for (int j = 0; j < 2; ++j)
        asrc[j] = xbf + (size_t)(m0 + (wid * 2 + j) * 16 + (lane >> 2)) * K_DIM +
                  8 * ((lane & 3) ^ ((lane >> 3) & 3));
    // B gll: lane covers row = wid*4 + (lane>>4),
    //        global dword col = 4*((lane&15) ^ ((wid&1)<<2)) + {0..3}
    const u32* bsrc = qwu + (size_t)(wid * 4 + (lane >> 4)) * N_DIM + n0 +
                      4 * ((lane & 15) ^ ((wid & 1) << 2));

    // ---- LDS read byte-offsets (within one buffer)
    const u32 aoff = (u32)((wm * 64 + l4) * 64 + ((c ^ ((l4 >> 1) & 3)) << 4));
    u32 boffs[2];
#pragma unroll
    for (int nf = 0; nf < 2; ++nf)
        boffs[nf] = (u32)(((c * 4) * 64 +
                           ((wn * 32 + nf * 16 + l4) ^ ((c & 1) << 4))) * 4);

    frag_cd acc[4][2];
#pragma unroll
    for (int i = 0; i < 4; ++i) {
        acc[i][0] = (frag_cd){0.f, 0.f, 0.f, 0.f};
        acc[i][1] = (frag_cd){0.f, 0.f, 0.f, 0.f};
    }

    auto stage = [&](int t_abs, int buf) {     // 3 x global_load_lds(16B)
#pragma unroll
        for (int j = 0; j < 2; ++j)
            gll16(asrc[j] + (size_t)t_abs * 32, &Alds[buf][(wid * 2 + j) * 64]);
        gll16(bsrc + (size_t)t_abs * 16 * N_DIM, &Blds[buf][wid * 256]);
    };

    auto compute = [&](int buf) {
        lds_cc* Ab = (lds_cc*)&Alds[buf][0];
        lds_cc* Bb = (lds_cc*)&Blds[buf][0];
        frag_ab afr[4];
        DSR128(afr[0], Ab + aoff, 0);
        DSR128(afr[1], Ab + aoff, 1024);
        DSR128(afr[2], Ab + aoff, 2048);
        DSR128(afr[3], Ab + aoff, 3072);
        u32x2 br[2][2];                  // [nf][pair], pair j={0,1},{2,3}
        DSR2(br[0][0], Bb + boffs[0], 0, 64);
        DSR2(br[0][1], Bb + boffs[0], 128, 192);
        DSR2(br[1][0], Bb + boffs[1], 0, 64);
        DSR2(br[1][1], Bb + boffs[1], 128, 192);
        asm volatile("s_waitcnt lgkmcnt(0)" ::: "memory");
        __builtin_amdgcn_sched_barrier(0);   // rule #18: pin MFMA after the wait
#pragma unroll
        for (int nf = 0; nf < 2; ++nf) {
            union { frag_ab f; u32 u[4]; } bb;
            bb.u[0] = BFCVT(br[nf][0][0]);
            bb.u[1] = BFCVT(br[nf][0][1]);
            bb.u[2] = BFCVT(br[nf][1][0]);
            bb.u[3] = BFCVT(br[nf][1][1]);
#pragma unroll
            for (int mf = 0; mf < 4; ++mf)
                acc[mf][nf] = __builtin_amdgcn_mfma_f32_16x16x32_bf16(
                    afr[mf], bb.f, acc[mf][nf], 0, 0, 0);
        }
    };

    // prologue: fill 2-deep prefetch
    stage(kb + 0, 0);
    stage(kb + 1, 1);

    int cur = 0;
    for (int t = 0; t < NTt; ++t) {
        int pbuf = cur + 2; if (pbuf >= 3) pbuf -= 3;
        if (t + 2 < NTt) {
            stage(kb + t + 2, pbuf);
            asm volatile("s_waitcnt vmcnt(6)" ::: "memory");   // tile t landed
        } else if (t + 1 < NTt) {
            asm volatile("s_waitcnt vmcnt(3)" ::: "memory");
        } else {
            asm volatile("s_waitcnt vmcnt(0)" ::: "memory");
        }
        __builtin_amdgcn_s_barrier();        // tile t's LDS writes visible
        __builtin_amdgcn_sched_barrier(0);
        compute(cur);
        asm volatile("" ::: "memory");
        __builtin_amdgcn_s_barrier();        // all waves done reading buf before re-stage
        ++cur; if (cur >= 3) cur -= 3;
    }

    // epilogue
    float sc[2], zp[2];
#pragma unroll
    for (int nf = 0; nf < 2; ++nf) {
        int n = n0 + wn * 32 + nf * 16 + l4;
        sc[nf] = scales[n];
        zp[nf] = zeroes[n] + 32.0f * sc[nf];
    }
    if (sp == 0) {
        float rs[4][4];
#pragma unroll
        for (int mf = 0; mf < 4; ++mf)
#pragma unroll
            for (int j = 0; j < 4; ++j)
                rs[mf][j] = rowsum[m0 + wm * 64 + mf * 16 + c * 4 + j];
#pragma unroll
        for (int mf = 0; mf < 4; ++mf)
#pragma unroll
            for (int nf = 0; nf < 2; ++nf)
#pragma unroll
                for (int j = 0; j < 4; ++j) {
                    int m = m0 + wm * 64 + mf * 16 + c * 4 + j;
                    out[(size_t)m * N_DIM + n0 + wn * 32 + nf * 16 + l4] =
                        sc[nf] * acc[mf][nf][j] - zp[nf] * rs[mf][j];
                }
    } else {
#pragma unroll
        for (int mf = 0; mf < 4; ++mf)
#pragma unroll
            for (int nf = 0; nf < 2; ++nf)
#pragma unroll
                for (int j = 0; j < 4; ++j) {
                    int m = m0 + wm * 64 + mf * 16 + c * 4 + j;
                    partial[(size_t)m * N_DIM + n0 + wn * 32 + nf * 16 + l4] =
                        sc[nf] * acc[mf][nf][j];
                }
    }
}

// Kernel 3: out += partial.  Exact cover of 256*11008 floats:
// 2752 blocks * 256 threads * 4 floats = 2,818,048.
__global__ __launch_bounds__(256) void reduce_kernel(float* __restrict__ out,
                                                     const float* __restrict__ partial) {
    size_t i = ((size_t)blockIdx.x * 256 + threadIdx.x) * 4;
    float4 o = *reinterpret_cast<float4*>(out + i);
    float4 p = *reinterpret_cast<const float4*>(partial + i);
    o.x += p.x; o.y += p.y; o.z += p.z; o.w += p.w;
    *reinterpret_cast<float4*>(out + i) = o;
}

extern "C" void kernel_launch(void* const* d_in, const int* in_sizes, int n_in,
                              void* d_out, int out_size, void* d_ws, size_t ws_size,
                              hipStream_t stream) {
    const float* x      = (const float*)d_in[0];
    const int*   qw     = (const int*)d_in[1];
    const float* scales = (const float*)d_in[2];
    const float* zeroes = (const float*)d_in[3];
    float* out = (float*)d_out;

    const size_t XBF_BYTES = (size_t)M_DIM * K_DIM * 2;   // 2 MB
    const size_t RS_OFF    = XBF_BYTES;                    // 1 KB
    const size_t P_OFF     = XBF_BYTES + 4096;
    const size_t P_BYTES   = (size_t)M_DIM * N_DIM * 4;    // 11.3 MB

    ushort* xbf    = (ushort*)d_ws;
    float*  rowsum = (float*)((char*)d_ws + RS_OFF);
    float*  part   = (float*)((char*)d_ws + P_OFF);

    const bool split2 = ws_size >= P_OFF + P_BYTES;

    prep_kernel<<<M_DIM, 256, 0, stream>>>(x, xbf, rowsum);
    if (split2) {
        gemm_kernel<<<688, 256, 0, stream>>>(qw, scales, zeroes, xbf, rowsum,
                                             out, part, 1);
        reduce_kernel<<<(M_DIM * N_DIM) / (256 * 4), 256, 0, stream>>>(out, part);
    } else {
        gemm_kernel<<<344, 256, 0, stream>>>(qw, scales, zeroes, xbf, rowsum,
                                             out, nullptr, 0);
    }
}